// Round 5
// baseline (1910.649 us; speedup 1.0000x reference)
//
#include <hip/hip_runtime.h>
#include <stdint.h>

#define N_SRCN 50000
#define N_DSTN 50000
#define NE     800000
#define HIDN   256
#define NEG    0.2f

typedef __attribute__((ext_vector_type(8)))  short short8;
typedef __attribute__((ext_vector_type(16))) float float16v;

__device__ __forceinline__ float bf2f(unsigned short u){
    union { unsigned u32; float f; } c; c.u32 = ((unsigned)u) << 16; return c.f;
}
__device__ __forceinline__ unsigned short f2bf(float f){
    union { float f; unsigned u; } c; c.f = f;
    unsigned r = c.u + 0x7fffu + ((c.u >> 16) & 1u);
    return (unsigned short)(r >> 16);
}
__device__ __forceinline__ float4 ld4b(const unsigned short* p){
    uint2 u = *reinterpret_cast<const uint2*>(p);
    float4 r;
    r.x = bf2f((unsigned short)(u.x & 0xffff));
    r.y = bf2f((unsigned short)(u.x >> 16));
    r.z = bf2f((unsigned short)(u.y & 0xffff));
    r.w = bf2f((unsigned short)(u.y >> 16));
    return r;
}
// async 16B global -> LDS (wave-uniform LDS base + lane*16 dest; PER-LANE src)
__device__ __forceinline__ void gload_lds16(const unsigned short* g, unsigned short* l){
    __builtin_amdgcn_global_load_lds(
        (const __attribute__((address_space(1))) void*)g,
        (__attribute__((address_space(3))) void*)l,
        16, 0, 0);
}

// ---- pack weights, input-indexed (coalesced reads, scattered 2B writes) ----
// Wt2: [which(3)][cb(8)][kk(4)][lane(64)][8]   (49152)
// Wf : [g(3)][cb(8)][kk(32)][lane(64)][8]      (393216), K=512 = [Wih|Whh]
__global__ void pack_kernel(const float* __restrict__ Wsrc, const float* __restrict__ Wdst,
                            const float* __restrict__ Wres, const float* __restrict__ Wih,
                            const float* __restrict__ Whh,
                            unsigned short* __restrict__ Wt2,
                            unsigned short* __restrict__ Wf){
    int i = blockIdx.x * 256 + threadIdx.x;
    if (i < 49152){
        int which = i >> 14, j = i & 16383;          // j = k*256 + c
        int k = j >> 8, c = j & 255;
        const float* W = (which == 0) ? Wsrc : (which == 1 ? Wdst : Wres);
        float v = W[j];
        int off = which * 16384 + (c >> 5) * 2048 + (k >> 4) * 512
                + (((k >> 3) & 1) * 32 + (c & 31)) * 8 + (k & 7);
        Wt2[off] = f2bf(v);
    } else if (i < 49152 + 196608){
        int o = i - 49152;                            // Wih flat: (g*256+c)*256+k
        int row = o >> 8, k = o & 255;
        int g = row >> 8, c = row & 255;
        float v = Wih[o];
        int off = g * 131072 + (c >> 5) * 16384 + (k >> 4) * 512
                + (((k >> 3) & 1) * 32 + (c & 31)) * 8 + (k & 7);
        Wf[off] = f2bf(v);
    } else if (i < 49152 + 393216){
        int o = i - 49152 - 196608;                   // Whh
        int row = o >> 8, k = o & 255;
        int g = row >> 8, c = row & 255;
        float v = Whh[o];
        int off = g * 131072 + (c >> 5) * 16384 + (16 + (k >> 4)) * 512
                + (((k >> 3) & 1) * 32 + (c & 31)) * 8 + (k & 7);
        Wf[off] = f2bf(v);
    }
}

// ---- fused projection GEMM (K=64), z selects {src, dst, res} --------------
__global__ __launch_bounds__(256) void proj_kernel(
        const float* __restrict__ Agt, const float* __restrict__ Aag,
        const unsigned short* __restrict__ Wt2,
        const float* __restrict__ bsrc, const float* __restrict__ bdst,
        const float* __restrict__ bres,
        unsigned short* __restrict__ fs, unsigned short* __restrict__ fd,
        unsigned short* __restrict__ resb){
    __shared__ unsigned short As[64 * 72];
    __shared__ unsigned short Cs[64 * 72];
    int z = blockIdx.z;
    const float* A = (z == 0) ? Agt : Aag;
    const float* bias = (z == 0) ? bsrc : (z == 1 ? bdst : bres);
    unsigned short* out = (z == 0) ? fs : (z == 1 ? fd : resb);
    const unsigned short* Wb = Wt2 + z * 16384;
    int tid = threadIdx.x;
    int m0 = blockIdx.y * 64;
    #pragma unroll
    for (int i = 0; i < 4; ++i){
        int ci = tid + i * 256;
        int row = ci >> 4;
        int k4 = (ci & 15) << 2;
        int gr = m0 + row; if (gr >= N_SRCN) gr = N_SRCN - 1;
        float4 v = *reinterpret_cast<const float4*>(A + (size_t)gr * 64 + k4);
        unsigned short* dp = As + row * 72 + k4;
        dp[0] = f2bf(v.x); dp[1] = f2bf(v.y); dp[2] = f2bf(v.z); dp[3] = f2bf(v.w);
    }
    __syncthreads();
    int lane = tid & 63, w = tid >> 6;
    int l31 = lane & 31, half = lane >> 5;
    int msub = (w & 1) * 32;
    int cbw = blockIdx.x * 2 + (w >> 1);
    const unsigned short* bb = Wb + cbw * 2048 + lane * 8;
    const unsigned short* ap = As + (msub + l31) * 72 + half * 8;
    float16v acc = {0,0,0,0,0,0,0,0,0,0,0,0,0,0,0,0};
    #pragma unroll
    for (int ks = 0; ks < 4; ++ks){
        short8 a = *reinterpret_cast<const short8*>(ap + ks * 16);
        short8 b = *reinterpret_cast<const short8*>(bb + ks * 512);
        acc = __builtin_amdgcn_mfma_f32_32x32x16_bf16(a, b, acc, 0, 0, 0);
    }
    float bv = bias[cbw * 32 + l31];
    int ccol = (w >> 1) * 32 + l31;
    #pragma unroll
    for (int r = 0; r < 16; ++r){
        int row = (r & 3) + 8 * (r >> 2) + 4 * half + msub;
        Cs[row * 72 + ccol] = f2bf(acc[r] + bv);
    }
    __syncthreads();
    int srow = tid >> 2, chunk = tid & 3;
    int gr2 = m0 + srow;
    if (gr2 < N_SRCN){
        const uint4* sp = reinterpret_cast<const uint4*>(Cs + srow * 72 + chunk * 16);
        uint4* gp = reinterpret_cast<uint4*>(out + (size_t)gr2 * 256 + blockIdx.x * 64 + chunk * 16);
        gp[0] = sp[0];
        gp[1] = sp[1];
    }
}

// ---- edge CSR build -------------------------------------------------------
__global__ void degree_kernel(const int* __restrict__ dst, int* __restrict__ deg){
    int i = blockIdx.x * 256 + threadIdx.x;
    if (i < NE) atomicAdd(&deg[dst[i]], 1);
}

__global__ void scan1_kernel(const int* __restrict__ deg, int* __restrict__ bsum){
    __shared__ int s[256];
    int tid = threadIdx.x;
    int i = blockIdx.x * 256 + tid;
    s[tid] = (i < N_DSTN) ? deg[i] : 0;
    __syncthreads();
    #pragma unroll
    for (int off = 128; off; off >>= 1){
        if (tid < off) s[tid] += s[tid + off];
        __syncthreads();
    }
    if (tid == 0) bsum[blockIdx.x] = s[0];
}

__global__ void scan2_kernel(const int* __restrict__ bsum, int* __restrict__ boff){
    __shared__ int s[256];
    int tid = threadIdx.x;
    int v = (tid < 196) ? bsum[tid] : 0;
    s[tid] = v;
    __syncthreads();
    #pragma unroll
    for (int off = 1; off < 256; off <<= 1){
        int t = (tid >= off) ? s[tid - off] : 0;
        __syncthreads();
        s[tid] += t;
        __syncthreads();
    }
    if (tid < 196) boff[tid] = s[tid] - v;
}

__global__ void scan3_kernel(const int* __restrict__ deg, const int* __restrict__ boff,
                             int* __restrict__ ptr, int* __restrict__ cursor){
    __shared__ int s[256];
    int tid = threadIdx.x;
    int i = blockIdx.x * 256 + tid;
    int v = (i < N_DSTN) ? deg[i] : 0;
    s[tid] = v;
    __syncthreads();
    #pragma unroll
    for (int off = 1; off < 256; off <<= 1){
        int t = (tid >= off) ? s[tid - off] : 0;
        __syncthreads();
        s[tid] += t;
        __syncthreads();
    }
    int ex = s[tid] - v + boff[blockIdx.x];
    if (i < N_DSTN){ ptr[i] = ex; cursor[i] = ex; }
}

__global__ void scatter_kernel(const int* __restrict__ src, const int* __restrict__ dst,
                               int* __restrict__ cursor, int* __restrict__ csr){
    int i = blockIdx.x * 256 + threadIdx.x;
    if (i < NE){
        int d = dst[i];
        int pos = atomicAdd(&cursor[d], 1);
        csr[pos] = src[i];
    }
}

// ---- per-dst aggregation, no online max (exp safe here), 4-deep pipeline --
__global__ __launch_bounds__(256) void aggregate_kernel(
        const unsigned short* __restrict__ fs, const unsigned short* __restrict__ fd,
        const unsigned short* __restrict__ res, const float* __restrict__ attn,
        const int* __restrict__ ptr, const int* __restrict__ deg,
        const int* __restrict__ csr, unsigned short* __restrict__ x){
    int wv = threadIdx.x >> 6;
    int d = blockIdx.x * 4 + wv;
    if (d >= N_DSTN) return;
    int lane = threadIdx.x & 63;
    int c4 = lane * 4;
    float4 fdv = ld4b(fd + (size_t)d * 256 + c4);
    float4 at = *reinterpret_cast<const float4*>(attn + (lane >> 4) * 64 + (lane & 15) * 4);
    int p = ptr[d], dg = deg[d];
    float l = 0.f;
    float4 acc = make_float4(0.f, 0.f, 0.f, 0.f);
    for (int base = 0; base < dg; base += 64){
        int cnt = min(64, dg - base);
        int sreg = (lane < cnt) ? csr[p + base + lane] : 0;
        float4 b0 = ld4b(fs + (size_t)__shfl(sreg, 0) * 256 + c4);
        float4 b1 = ld4b(fs + (size_t)__shfl(sreg, 1 & 63) * 256 + c4);
        float4 b2 = ld4b(fs + (size_t)__shfl(sreg, 2 & 63) * 256 + c4);
        float4 b3 = ld4b(fs + (size_t)__shfl(sreg, 3 & 63) * 256 + c4);
        for (int j = 0; j < cnt; j += 4){
            float4 n0 = ld4b(fs + (size_t)__shfl(sreg, (j + 4) & 63) * 256 + c4);
            float4 n1 = ld4b(fs + (size_t)__shfl(sreg, (j + 5) & 63) * 256 + c4);
            float4 n2 = ld4b(fs + (size_t)__shfl(sreg, (j + 6) & 63) * 256 + c4);
            float4 n3 = ld4b(fs + (size_t)__shfl(sreg, (j + 7) & 63) * 256 + c4);
#define PROC(BV, T) { \
            float ex = BV.x + fdv.x; ex = ex > 0.f ? ex : NEG * ex; \
            float ey = BV.y + fdv.y; ey = ey > 0.f ? ey : NEG * ey; \
            float ez = BV.z + fdv.z; ez = ez > 0.f ? ez : NEG * ez; \
            float ew = BV.w + fdv.w; ew = ew > 0.f ? ew : NEG * ew; \
            float part = ex * at.x + ey * at.y + ez * at.z + ew * at.w; \
            part += __shfl_xor(part, 1); \
            part += __shfl_xor(part, 2); \
            part += __shfl_xor(part, 4); \
            part += __shfl_xor(part, 8); \
            float wgt = ((j + (T)) < cnt) ? __expf(part) : 0.f; \
            l += wgt; \
            acc.x = fmaf(wgt, BV.x, acc.x); \
            acc.y = fmaf(wgt, BV.y, acc.y); \
            acc.z = fmaf(wgt, BV.z, acc.z); \
            acc.w = fmaf(wgt, BV.w, acc.w); }
            PROC(b0, 0) PROC(b1, 1) PROC(b2, 2) PROC(b3, 3)
#undef PROC
            b0 = n0; b1 = n1; b2 = n2; b3 = n3;
        }
    }
    float inv = (l > 0.f) ? 1.f / l : 0.f;
    float4 rv = ld4b(res + (size_t)d * 256 + c4);
    float xx = fmaxf(fmaf(acc.x, inv, rv.x), 0.f);
    float xy = fmaxf(fmaf(acc.y, inv, rv.y), 0.f);
    float xz = fmaxf(fmaf(acc.z, inv, rv.z), 0.f);
    float xw = fmaxf(fmaf(acc.w, inv, rv.w), 0.f);
    uint2 o;
    o.x = (unsigned)f2bf(xx) | ((unsigned)f2bf(xy) << 16);
    o.y = (unsigned)f2bf(xz) | ((unsigned)f2bf(xw) << 16);
    *reinterpret_cast<uint2*>(x + (size_t)d * 256 + c4) = o;
}

// ---- GRU v9: 80KB LDS -> 2 blocks/CU; K-half A-tile with mid-loop swap ----
// v7/v8 post-mortem: 136KB LDS = 1 block/CU; per-phase latency fully exposed
// (counted vmcnt AND conflict-free LDS both null). Fix = occupancy:
//   A-tile 32KB (one K-half at a time): X half staged in prologue via
//   global_load_lds with PRE-SWIZZLED per-lane source (linear LDS dest);
//   H half loaded to regs at p==14 (issue-early), cvt+ds_write at the p==16
//   boundary (write-late, hidden under compute).
//   B double-buffer 2x24KB, issue 1 phase ahead, vmcnt(0) at phase top
//   (full-phase cover; v8 proved extra depth buys nothing intra-block).
// Total 32+48 = 80KB = exactly 2 blocks/CU (32 waves). Cross-block overlap
// fills the per-phase stalls no intra-block scheme could.
__global__ __launch_bounds__(1024, 8) void gru_kernel(
        const unsigned short* __restrict__ Xb,
        const float* __restrict__ H0, const unsigned short* __restrict__ Wf,
        const float* __restrict__ bih, const float* __restrict__ bhh,
        float* __restrict__ outH){
    __shared__ unsigned short As[64 * 256];      // 32KB: one K-half, XOR-swizzled
    __shared__ unsigned short Bs[2 * 12288];     // 48KB: dbuf, 24 slices x 1KB
    int tid = threadIdx.x;
    int m0 = blockIdx.x << 6;
    int w = tid >> 6, lane = tid & 63;

    // ---- prologue: X half via async gload (pre-swizzled SOURCE, linear dest)
    #pragma unroll
    for (int i = 0; i < 2; ++i){
        int idx = w + i * 16;                    // 32 x 1KB chunks = 64 rows
        int row = 2 * idx + (lane >> 5);
        int gr = m0 + row; if (gr >= N_DSTN) gr = N_DSTN - 1;
        int j = lane & 31;
        const unsigned short* src = Xb + (size_t)gr * 256 + ((j ^ (row & 15)) << 3);
        gload_lds16(src, As + idx * 512);        // dest: lane*16B linear
    }
    // B prologue: phase 0 slices (12 staging waves x 2 slices)
    int s0 = 2 * w, s1 = 2 * w + 1;
    const unsigned short* g0 = Wf + (s0 >> 3) * 131072 + (s0 & 7) * 16384 + lane * 8;
    const unsigned short* g1 = Wf + (s1 >> 3) * 131072 + (s1 & 7) * 16384 + lane * 8;
    if (w < 12){
        gload_lds16(g0, Bs + s0 * 512);
        gload_lds16(g1, Bs + s1 * 512);
    }
    asm volatile("s_waitcnt vmcnt(0)" ::: "memory");
    __syncthreads();

    int l31 = lane & 31, half = lane >> 5;
    int rt = w >> 3, ct = w & 7;                 // 2 row-tiles x 8 col-tiles
    int arow = rt * 32 + l31;
    int rl = arow & 15;
    const unsigned short* apb = As + arow * 256;
    // H preload geometry (16 f32 per thread = one 64B segment)
    int hrow = tid >> 4, hseg = tid & 15;
    int hgr = m0 + hrow; if (hgr >= N_DSTN) hgr = N_DSTN - 1;
    float4 h0r, h1r, h2r, h3r;
    float16v zv = {0,0,0,0,0,0,0,0,0,0,0,0,0,0,0,0};
    float16v ar = zv, az = zv, anx = zv, anh = zv;
    #pragma unroll
    for (int p = 0; p < 32; ++p){
        asm volatile("s_waitcnt vmcnt(0)" ::: "memory");  // phase-p B staged
        __builtin_amdgcn_s_barrier();
        __builtin_amdgcn_sched_barrier(0);
        if (p == 16){
            // write preloaded H (f32->bf16) into As, swizzled; fence before reads
            uint4 o;
            o.x = (unsigned)f2bf(h0r.x) | ((unsigned)f2bf(h0r.y) << 16);
            o.y = (unsigned)f2bf(h0r.z) | ((unsigned)f2bf(h0r.w) << 16);
            o.z = (unsigned)f2bf(h1r.x) | ((unsigned)f2bf(h1r.y) << 16);
            o.w = (unsigned)f2bf(h1r.z) | ((unsigned)f2bf(h1r.w) << 16);
            int c0 = hseg * 2;
            *reinterpret_cast<uint4*>(As + hrow * 256 + ((c0 ^ (hrow & 15)) << 3)) = o;
            o.x = (unsigned)f2bf(h2r.x) | ((unsigned)f2bf(h2r.y) << 16);
            o.y = (unsigned)f2bf(h2r.z) | ((unsigned)f2bf(h2r.w) << 16);
            o.z = (unsigned)f2bf(h3r.x) | ((unsigned)f2bf(h3r.y) << 16);
            o.w = (unsigned)f2bf(h3r.z) | ((unsigned)f2bf(h3r.w) << 16);
            *reinterpret_cast<uint4*>(As + hrow * 256 + (((c0 + 1) ^ (hrow & 15)) << 3)) = o;
            asm volatile("s_waitcnt lgkmcnt(0)" ::: "memory");
            __builtin_amdgcn_s_barrier();
            __builtin_amdgcn_sched_barrier(0);
        }
        // issue stage for phase p+1 (its buffer was consumed in phase p-1)
        if (p + 1 < 32 && w < 12){
            unsigned short* db = Bs + ((p + 1) & 1) * 12288;
            gload_lds16(g0 + (p + 1) * 512, db + s0 * 512);
            gload_lds16(g1 + (p + 1) * 512, db + s1 * 512);
        }
        if (p == 14){
            // issue H loads early; consumed (with auto waitcnt) at p==16
            const float* hp = H0 + (size_t)hgr * 256 + hseg * 16;
            h0r = *reinterpret_cast<const float4*>(hp);
            h1r = *reinterpret_cast<const float4*>(hp + 4);
            h2r = *reinterpret_cast<const float4*>(hp + 8);
            h3r = *reinterpret_cast<const float4*>(hp + 12);
        }
        // compute phase p
        const unsigned short* bp = Bs + (p & 1) * 12288;
        int kl = p & 15;
        short8 a  = *reinterpret_cast<const short8*>(apb + (((kl * 2 + half) ^ rl) << 3));
        short8 vr = *reinterpret_cast<const short8*>(bp + (0 * 8 + ct) * 512 + lane * 8);
        short8 vz = *reinterpret_cast<const short8*>(bp + (1 * 8 + ct) * 512 + lane * 8);
        short8 vn = *reinterpret_cast<const short8*>(bp + (2 * 8 + ct) * 512 + lane * 8);
        __builtin_amdgcn_s_setprio(1);
        ar = __builtin_amdgcn_mfma_f32_32x32x16_bf16(a, vr, ar, 0, 0, 0);
        az = __builtin_amdgcn_mfma_f32_32x32x16_bf16(a, vz, az, 0, 0, 0);
        if (p < 16) anx = __builtin_amdgcn_mfma_f32_32x32x16_bf16(a, vn, anx, 0, 0, 0);
        else        anh = __builtin_amdgcn_mfma_f32_32x32x16_bf16(a, vn, anh, 0, 0, 0);
        __builtin_amdgcn_s_setprio(0);
    }
    // fused GRU epilogue; H0 rows are L2-hot (loaded at p==14 by this block)
    int cg = ct * 32 + l31;
    float rb = bih[cg] + bhh[cg];
    float zb = bih[256 + cg] + bhh[256 + cg];
    float bin = bih[512 + cg], bhn = bhh[512 + cg];
    #pragma unroll
    for (int r = 0; r < 16; ++r){
        int m = m0 + rt * 32 + (r & 3) + 8 * (r >> 2) + 4 * half;
        if (m < N_DSTN){
            float h0v = H0[(size_t)m * 256 + cg];
            float rrg = 1.f / (1.f + __expf(-(ar[r] + rb)));
            float zg  = 1.f / (1.f + __expf(-(az[r] + zb)));
            float nx = anx[r] + bin + rrg * (anh[r] + bhn);
            float tm = __expf(-2.f * fabsf(nx));
            float nn = (1.f - tm) / (1.f + tm);
            nn = (nx >= 0.f) ? nn : -nn;
            outH[(size_t)m * 256 + cg] = (1.f - zg) * nn + zg * h0v;
        }
    }
}

// ---- logits = h @ W_out + b_out ------------------------------------------
__global__ __launch_bounds__(256) void logits_kernel(
        const float* __restrict__ H, const float* __restrict__ Wout,
        const float* __restrict__ bout, float* __restrict__ outL){
    __shared__ float Hl[16 * 260];
    __shared__ float Wl[16 * 260];
    int tid = threadIdx.x;
    int m0 = blockIdx.x * 16;
    #pragma unroll
    for (int i = 0; i < 4; ++i){
        int ci = tid + i * 256;
        int row = ci >> 6;
        int c4 = (ci & 63) << 2;
        int gr = m0 + row; if (gr >= N_DSTN) gr = N_DSTN - 1;
        float4 v = *reinterpret_cast<const float4*>(H + (size_t)gr * 256 + c4);
        float* dp = Hl + row * 260 + c4;
        dp[0] = v.x; dp[1] = v.y; dp[2] = v.z; dp[3] = v.w;
    }
    #pragma unroll
    for (int i = 0; i < 16; ++i){
        int ci = tid + i * 256;
        int c = ci >> 4, j = ci & 15;
        Wl[j * 260 + c] = Wout[c * 16 + j];
    }
    __syncthreads();
    int row = tid >> 4, j = tid & 15;
    const float* hr = Hl + row * 260;
    const float* wr = Wl + j * 260;
    float acc = bout[j];
    #pragma unroll
    for (int c = 0; c < 256; c += 4){
        float4 hv = *reinterpret_cast<const float4*>(hr + c);
        float4 wv = *reinterpret_cast<const float4*>(wr + c);
        acc = fmaf(hv.x, wv.x, fmaf(hv.y, wv.y, fmaf(hv.z, wv.z, fmaf(hv.w, wv.w, acc))));
    }
    int m = m0 + row;
    if (m < N_DSTN) outL[m * 16 + j] = acc;
}

extern "C" void kernel_launch(void* const* d_in, const int* in_sizes, int n_in,
                              void* d_out, int out_size, void* d_ws, size_t ws_size,
                              hipStream_t stream){
    const float* feat_gt = (const float*)d_in[0];
    const float* feat_ag = (const float*)d_in[1];
    const float* h0      = (const float*)d_in[2];
    const int*   e_src   = (const int*)d_in[3];
    const int*   e_dst   = (const int*)d_in[4];
    const float* W_src   = (const float*)d_in[5];
    const float* b_src   = (const float*)d_in[6];
    const float* W_dst   = (const float*)d_in[7];
    const float* b_dst   = (const float*)d_in[8];
    const float* attn    = (const float*)d_in[9];
    const float* W_res   = (const float*)d_in[10];
    const float* b_res   = (const float*)d_in[11];
    const float* W_ih    = (const float*)d_in[12];
    const float* W_hh    = (const float*)d_in[13];
    const float* b_ih    = (const float*)d_in[14];
    const float* b_hh    = (const float*)d_in[15];
    const float* W_out   = (const float*)d_in[16];
    const float* b_out   = (const float*)d_in[17];

    float* outL = (float*)d_out;
    float* outH = outL + (size_t)N_DSTN * 16;

    char* ws = (char*)d_ws;
    size_t off = 0;
    auto alloc = [&](size_t bytes) -> void* {
        void* p = ws + off; off = (off + bytes + 255) & ~(size_t)255; return p;
    };
    unsigned short* fs   = (unsigned short*)alloc((size_t)N_SRCN * 256 * 2);
    unsigned short* fd   = (unsigned short*)alloc((size_t)N_DSTN * 256 * 2);
    unsigned short* res  = (unsigned short*)alloc((size_t)N_DSTN * 256 * 2);
    unsigned short* xb   = (unsigned short*)alloc((size_t)N_DSTN * 256 * 2);
    unsigned short* Wt2  = (unsigned short*)alloc(49152 * 2);
    unsigned short* Wf   = (unsigned short*)alloc(393216 * 2);
    int* deg    = (int*)alloc(N_DSTN * 4);
    int* ptr    = (int*)alloc(N_DSTN * 4);
    int* cursor = (int*)alloc(N_DSTN * 4);
    int* csr    = (int*)alloc((size_t)NE * 4);
    int* bsum   = (int*)alloc(256 * 4);
    int* boff   = (int*)alloc(256 * 4);

    hipMemsetAsync(deg, 0, N_DSTN * 4, stream);
    pack_kernel<<<1728, 256, 0, stream>>>(W_src, W_dst, W_res, W_ih, W_hh, Wt2, Wf);

    proj_kernel<<<dim3(4, 782, 3), 256, 0, stream>>>(feat_gt, feat_ag, Wt2,
                                                     b_src, b_dst, b_res, fs, fd, res);

    degree_kernel<<<3125, 256, 0, stream>>>(e_dst, deg);
    scan1_kernel<<<196, 256, 0, stream>>>(deg, bsum);
    scan2_kernel<<<1, 256, 0, stream>>>(bsum, boff);
    scan3_kernel<<<196, 256, 0, stream>>>(deg, boff, ptr, cursor);
    scatter_kernel<<<3125, 256, 0, stream>>>(e_src, e_dst, cursor, csr);
    aggregate_kernel<<<12500, 256, 0, stream>>>(fs, fd, res, attn, ptr, deg, csr, xb);

    gru_kernel<<<782, 1024, 0, stream>>>(xb, h0, Wf, b_ih, b_hh, outH);
    logits_kernel<<<3125, 256, 0, stream>>>(outH, W_out, b_out, outL);
}

// Round 6
// 456.813 us; speedup vs baseline: 4.1826x; 4.1826x over previous
//
#include <hip/hip_runtime.h>
#include <stdint.h>

#define N_SRCN 50000
#define N_DSTN 50000
#define NE     800000
#define HIDN   256
#define NEG    0.2f

typedef __attribute__((ext_vector_type(8)))  short short8;
typedef __attribute__((ext_vector_type(16))) float float16v;

__device__ __forceinline__ float bf2f(unsigned short u){
    union { unsigned u32; float f; } c; c.u32 = ((unsigned)u) << 16; return c.f;
}
__device__ __forceinline__ unsigned short f2bf(float f){
    union { float f; unsigned u; } c; c.f = f;
    unsigned r = c.u + 0x7fffu + ((c.u >> 16) & 1u);
    return (unsigned short)(r >> 16);
}
__device__ __forceinline__ float4 ld4b(const unsigned short* p){
    uint2 u = *reinterpret_cast<const uint2*>(p);
    float4 r;
    r.x = bf2f((unsigned short)(u.x & 0xffff));
    r.y = bf2f((unsigned short)(u.x >> 16));
    r.z = bf2f((unsigned short)(u.y & 0xffff));
    r.w = bf2f((unsigned short)(u.y >> 16));
    return r;
}
// async 16B global -> LDS (wave-uniform LDS base + lane*16 dest; PER-LANE src)
__device__ __forceinline__ void gload_lds16(const unsigned short* g, unsigned short* l){
    __builtin_amdgcn_global_load_lds(
        (const __attribute__((address_space(1))) void*)g,
        (__attribute__((address_space(3))) void*)l,
        16, 0, 0);
}

// ---- pack weights, input-indexed (coalesced reads, scattered 2B writes) ----
// Wt2: [which(3)][cb(8)][kk(4)][lane(64)][8]   (49152)
// Wf : [g(3)][cb(8)][kk(32)][lane(64)][8]      (393216), K=512 = [Wih|Whh]
__global__ void pack_kernel(const float* __restrict__ Wsrc, const float* __restrict__ Wdst,
                            const float* __restrict__ Wres, const float* __restrict__ Wih,
                            const float* __restrict__ Whh,
                            unsigned short* __restrict__ Wt2,
                            unsigned short* __restrict__ Wf){
    int i = blockIdx.x * 256 + threadIdx.x;
    if (i < 49152){
        int which = i >> 14, j = i & 16383;          // j = k*256 + c
        int k = j >> 8, c = j & 255;
        const float* W = (which == 0) ? Wsrc : (which == 1 ? Wdst : Wres);
        float v = W[j];
        int off = which * 16384 + (c >> 5) * 2048 + (k >> 4) * 512
                + (((k >> 3) & 1) * 32 + (c & 31)) * 8 + (k & 7);
        Wt2[off] = f2bf(v);
    } else if (i < 49152 + 196608){
        int o = i - 49152;                            // Wih flat: (g*256+c)*256+k
        int row = o >> 8, k = o & 255;
        int g = row >> 8, c = row & 255;
        float v = Wih[o];
        int off = g * 131072 + (c >> 5) * 16384 + (k >> 4) * 512
                + (((k >> 3) & 1) * 32 + (c & 31)) * 8 + (k & 7);
        Wf[off] = f2bf(v);
    } else if (i < 49152 + 393216){
        int o = i - 49152 - 196608;                   // Whh
        int row = o >> 8, k = o & 255;
        int g = row >> 8, c = row & 255;
        float v = Whh[o];
        int off = g * 131072 + (c >> 5) * 16384 + (16 + (k >> 4)) * 512
                + (((k >> 3) & 1) * 32 + (c & 31)) * 8 + (k & 7);
        Wf[off] = f2bf(v);
    }
}

// ---- fused projection GEMM (K=64), z selects {src, dst, res} --------------
__global__ __launch_bounds__(256) void proj_kernel(
        const float* __restrict__ Agt, const float* __restrict__ Aag,
        const unsigned short* __restrict__ Wt2,
        const float* __restrict__ bsrc, const float* __restrict__ bdst,
        const float* __restrict__ bres,
        unsigned short* __restrict__ fs, unsigned short* __restrict__ fd,
        unsigned short* __restrict__ resb){
    __shared__ unsigned short As[64 * 72];
    __shared__ unsigned short Cs[64 * 72];
    int z = blockIdx.z;
    const float* A = (z == 0) ? Agt : Aag;
    const float* bias = (z == 0) ? bsrc : (z == 1 ? bdst : bres);
    unsigned short* out = (z == 0) ? fs : (z == 1 ? fd : resb);
    const unsigned short* Wb = Wt2 + z * 16384;
    int tid = threadIdx.x;
    int m0 = blockIdx.y * 64;
    #pragma unroll
    for (int i = 0; i < 4; ++i){
        int ci = tid + i * 256;
        int row = ci >> 4;
        int k4 = (ci & 15) << 2;
        int gr = m0 + row; if (gr >= N_SRCN) gr = N_SRCN - 1;
        float4 v = *reinterpret_cast<const float4*>(A + (size_t)gr * 64 + k4);
        unsigned short* dp = As + row * 72 + k4;
        dp[0] = f2bf(v.x); dp[1] = f2bf(v.y); dp[2] = f2bf(v.z); dp[3] = f2bf(v.w);
    }
    __syncthreads();
    int lane = tid & 63, w = tid >> 6;
    int l31 = lane & 31, half = lane >> 5;
    int msub = (w & 1) * 32;
    int cbw = blockIdx.x * 2 + (w >> 1);
    const unsigned short* bb = Wb + cbw * 2048 + lane * 8;
    const unsigned short* ap = As + (msub + l31) * 72 + half * 8;
    float16v acc = {0,0,0,0,0,0,0,0,0,0,0,0,0,0,0,0};
    #pragma unroll
    for (int ks = 0; ks < 4; ++ks){
        short8 a = *reinterpret_cast<const short8*>(ap + ks * 16);
        short8 b = *reinterpret_cast<const short8*>(bb + ks * 512);
        acc = __builtin_amdgcn_mfma_f32_32x32x16_bf16(a, b, acc, 0, 0, 0);
    }
    float bv = bias[cbw * 32 + l31];
    int ccol = (w >> 1) * 32 + l31;
    #pragma unroll
    for (int r = 0; r < 16; ++r){
        int row = (r & 3) + 8 * (r >> 2) + 4 * half + msub;
        Cs[row * 72 + ccol] = f2bf(acc[r] + bv);
    }
    __syncthreads();
    int srow = tid >> 2, chunk = tid & 3;
    int gr2 = m0 + srow;
    if (gr2 < N_SRCN){
        const uint4* sp = reinterpret_cast<const uint4*>(Cs + srow * 72 + chunk * 16);
        uint4* gp = reinterpret_cast<uint4*>(out + (size_t)gr2 * 256 + blockIdx.x * 64 + chunk * 16);
        gp[0] = sp[0];
        gp[1] = sp[1];
    }
}

// ---- edge CSR build -------------------------------------------------------
__global__ void degree_kernel(const int* __restrict__ dst, int* __restrict__ deg){
    int i = blockIdx.x * 256 + threadIdx.x;
    if (i < NE) atomicAdd(&deg[dst[i]], 1);
}

__global__ void scan1_kernel(const int* __restrict__ deg, int* __restrict__ bsum){
    __shared__ int s[256];
    int tid = threadIdx.x;
    int i = blockIdx.x * 256 + tid;
    s[tid] = (i < N_DSTN) ? deg[i] : 0;
    __syncthreads();
    #pragma unroll
    for (int off = 128; off; off >>= 1){
        if (tid < off) s[tid] += s[tid + off];
        __syncthreads();
    }
    if (tid == 0) bsum[blockIdx.x] = s[0];
}

__global__ void scan2_kernel(const int* __restrict__ bsum, int* __restrict__ boff){
    __shared__ int s[256];
    int tid = threadIdx.x;
    int v = (tid < 196) ? bsum[tid] : 0;
    s[tid] = v;
    __syncthreads();
    #pragma unroll
    for (int off = 1; off < 256; off <<= 1){
        int t = (tid >= off) ? s[tid - off] : 0;
        __syncthreads();
        s[tid] += t;
        __syncthreads();
    }
    if (tid < 196) boff[tid] = s[tid] - v;
}

__global__ void scan3_kernel(const int* __restrict__ deg, const int* __restrict__ boff,
                             int* __restrict__ ptr, int* __restrict__ cursor){
    __shared__ int s[256];
    int tid = threadIdx.x;
    int i = blockIdx.x * 256 + tid;
    int v = (i < N_DSTN) ? deg[i] : 0;
    s[tid] = v;
    __syncthreads();
    #pragma unroll
    for (int off = 1; off < 256; off <<= 1){
        int t = (tid >= off) ? s[tid - off] : 0;
        __syncthreads();
        s[tid] += t;
        __syncthreads();
    }
    int ex = s[tid] - v + boff[blockIdx.x];
    if (i < N_DSTN){ ptr[i] = ex; cursor[i] = ex; }
}

__global__ void scatter_kernel(const int* __restrict__ src, const int* __restrict__ dst,
                               int* __restrict__ cursor, int* __restrict__ csr){
    int i = blockIdx.x * 256 + threadIdx.x;
    if (i < NE){
        int d = dst[i];
        int pos = atomicAdd(&cursor[d], 1);
        csr[pos] = src[i];
    }
}

// ---- per-dst aggregation, no online max (exp safe here), 4-deep pipeline --
__global__ __launch_bounds__(256) void aggregate_kernel(
        const unsigned short* __restrict__ fs, const unsigned short* __restrict__ fd,
        const unsigned short* __restrict__ res, const float* __restrict__ attn,
        const int* __restrict__ ptr, const int* __restrict__ deg,
        const int* __restrict__ csr, unsigned short* __restrict__ x){
    int wv = threadIdx.x >> 6;
    int d = blockIdx.x * 4 + wv;
    if (d >= N_DSTN) return;
    int lane = threadIdx.x & 63;
    int c4 = lane * 4;
    float4 fdv = ld4b(fd + (size_t)d * 256 + c4);
    float4 at = *reinterpret_cast<const float4*>(attn + (lane >> 4) * 64 + (lane & 15) * 4);
    int p = ptr[d], dg = deg[d];
    float l = 0.f;
    float4 acc = make_float4(0.f, 0.f, 0.f, 0.f);
    for (int base = 0; base < dg; base += 64){
        int cnt = min(64, dg - base);
        int sreg = (lane < cnt) ? csr[p + base + lane] : 0;
        float4 b0 = ld4b(fs + (size_t)__shfl(sreg, 0) * 256 + c4);
        float4 b1 = ld4b(fs + (size_t)__shfl(sreg, 1 & 63) * 256 + c4);
        float4 b2 = ld4b(fs + (size_t)__shfl(sreg, 2 & 63) * 256 + c4);
        float4 b3 = ld4b(fs + (size_t)__shfl(sreg, 3 & 63) * 256 + c4);
        for (int j = 0; j < cnt; j += 4){
            float4 n0 = ld4b(fs + (size_t)__shfl(sreg, (j + 4) & 63) * 256 + c4);
            float4 n1 = ld4b(fs + (size_t)__shfl(sreg, (j + 5) & 63) * 256 + c4);
            float4 n2 = ld4b(fs + (size_t)__shfl(sreg, (j + 6) & 63) * 256 + c4);
            float4 n3 = ld4b(fs + (size_t)__shfl(sreg, (j + 7) & 63) * 256 + c4);
#define PROC(BV, T) { \
            float ex = BV.x + fdv.x; ex = ex > 0.f ? ex : NEG * ex; \
            float ey = BV.y + fdv.y; ey = ey > 0.f ? ey : NEG * ey; \
            float ez = BV.z + fdv.z; ez = ez > 0.f ? ez : NEG * ez; \
            float ew = BV.w + fdv.w; ew = ew > 0.f ? ew : NEG * ew; \
            float part = ex * at.x + ey * at.y + ez * at.z + ew * at.w; \
            part += __shfl_xor(part, 1); \
            part += __shfl_xor(part, 2); \
            part += __shfl_xor(part, 4); \
            part += __shfl_xor(part, 8); \
            float wgt = ((j + (T)) < cnt) ? __expf(part) : 0.f; \
            l += wgt; \
            acc.x = fmaf(wgt, BV.x, acc.x); \
            acc.y = fmaf(wgt, BV.y, acc.y); \
            acc.z = fmaf(wgt, BV.z, acc.z); \
            acc.w = fmaf(wgt, BV.w, acc.w); }
            PROC(b0, 0) PROC(b1, 1) PROC(b2, 2) PROC(b3, 3)
#undef PROC
            b0 = n0; b1 = n1; b2 = n2; b3 = n3;
        }
    }
    float inv = (l > 0.f) ? 1.f / l : 0.f;
    float4 rv = ld4b(res + (size_t)d * 256 + c4);
    float xx = fmaxf(fmaf(acc.x, inv, rv.x), 0.f);
    float xy = fmaxf(fmaf(acc.y, inv, rv.y), 0.f);
    float xz = fmaxf(fmaf(acc.z, inv, rv.z), 0.f);
    float xw = fmaxf(fmaf(acc.w, inv, rv.w), 0.f);
    uint2 o;
    o.x = (unsigned)f2bf(xx) | ((unsigned)f2bf(xy) << 16);
    o.y = (unsigned)f2bf(xz) | ((unsigned)f2bf(xw) << 16);
    *reinterpret_cast<uint2*>(x + (size_t)d * 256 + c4) = o;
}

// ---- GRU v10: 32-row x 256-col, 512 thr / 8 waves, 80KB -> 2 blocks/CU ----
// v9 post-mortem: __launch_bounds__(1024,8) capped regs at 64/wave -> total
// spill (3.9GB scratch writes). Hard constraint learned: 2 blocks/CU at 128
// regs/wave requires <=8-wave blocks. v10: 512 threads, wave w owns ct=w
// (32x32 x 4 gate-accs = 64 regs; cap 128 via __launch_bounds__(512,4)).
// LDS 80KB = A 32KB (32 rows x K=512, X region + H region, staged ONCE in
// prologue: X via pre-swizzled-source global_load_lds, H reg-staged
// f32->bf16) + B dbuf 2x24KB. Exactly 2 blocks/CU: cross-block overlap
// fills the per-phase barrier stalls v7/v8 proved unfillable intra-block.
__global__ __launch_bounds__(512, 4) void gru_kernel(
        const unsigned short* __restrict__ Xb,
        const float* __restrict__ H0, const unsigned short* __restrict__ Wf,
        const float* __restrict__ bih, const float* __restrict__ bhh,
        float* __restrict__ outH){
    __shared__ unsigned short As[2 * 32 * 256];  // 32KB: [X 32x256][H 32x256]
    __shared__ unsigned short Bs[2 * 12288];     // 48KB: dbuf, 24 slices x 1KB
    int tid = threadIdx.x;
    int m0 = blockIdx.x << 5;                    // 32 rows/block
    int w = tid >> 6, lane = tid & 63;

    // ---- prologue A: X region via async gload (swizzled SOURCE, linear dest)
    // 16 chunks of 1KB; chunk g = rows {2g, 2g+1} x 256 shorts (X half)
    #pragma unroll
    for (int i = 0; i < 2; ++i){
        int g = w + i * 8;                       // 0..15
        int row = 2 * g + (lane >> 5);
        int gr = m0 + row; if (gr >= N_DSTN) gr = N_DSTN - 1;
        int j = lane & 31;                       // 16B chunk within row's X half
        const unsigned short* src = Xb + (size_t)gr * 256 + ((j ^ (row & 15)) << 3);
        gload_lds16(src, As + g * 512);          // dest: base + lane*16B linear
    }
    // ---- prologue B: phase-0 slices (8 waves x 3 slices of 1KB)
    int s0 = 3 * w, s1 = 3 * w + 1, s2 = 3 * w + 2;
    const unsigned short* g0 = Wf + (s0 >> 3) * 131072 + (s0 & 7) * 16384 + lane * 8;
    const unsigned short* g1 = Wf + (s1 >> 3) * 131072 + (s1 & 7) * 16384 + lane * 8;
    const unsigned short* g2 = Wf + (s2 >> 3) * 131072 + (s2 & 7) * 16384 + lane * 8;
    gload_lds16(g0, Bs + s0 * 512);
    gload_lds16(g1, Bs + s1 * 512);
    gload_lds16(g2, Bs + s2 * 512);
    // ---- prologue A: H region reg-staged f32->bf16 (once per element)
    {
        int hrow = tid >> 4, hseg = tid & 15;    // 32 rows x 16 segs of 16 f32
        int hgr = m0 + hrow; if (hgr >= N_DSTN) hgr = N_DSTN - 1;
        const float* hp = H0 + (size_t)hgr * 256 + hseg * 16;
        float4 f0 = *reinterpret_cast<const float4*>(hp);
        float4 f1 = *reinterpret_cast<const float4*>(hp + 4);
        float4 f2 = *reinterpret_cast<const float4*>(hp + 8);
        float4 f3 = *reinterpret_cast<const float4*>(hp + 12);
        int rl = hrow & 15;
        int c0 = hseg * 2;
        uint4 o;
        o.x = (unsigned)f2bf(f0.x) | ((unsigned)f2bf(f0.y) << 16);
        o.y = (unsigned)f2bf(f0.z) | ((unsigned)f2bf(f0.w) << 16);
        o.z = (unsigned)f2bf(f1.x) | ((unsigned)f2bf(f1.y) << 16);
        o.w = (unsigned)f2bf(f1.z) | ((unsigned)f2bf(f1.w) << 16);
        *reinterpret_cast<uint4*>(As + 8192 + hrow * 256 + ((c0 ^ rl) << 3)) = o;
        o.x = (unsigned)f2bf(f2.x) | ((unsigned)f2bf(f2.y) << 16);
        o.y = (unsigned)f2bf(f2.z) | ((unsigned)f2bf(f2.w) << 16);
        o.z = (unsigned)f2bf(f3.x) | ((unsigned)f2bf(f3.y) << 16);
        o.w = (unsigned)f2bf(f3.z) | ((unsigned)f2bf(f3.w) << 16);
        *reinterpret_cast<uint4*>(As + 8192 + hrow * 256 + (((c0 + 1) ^ rl) << 3)) = o;
    }
    asm volatile("s_waitcnt vmcnt(0) lgkmcnt(0)" ::: "memory");
    __syncthreads();

    int l31 = lane & 31, half = lane >> 5;
    int ct = w;                                  // 8 col-tiles of 32
    int arow = l31;                              // 32 rows
    int rl = arow & 15;
    float16v zv = {0,0,0,0,0,0,0,0,0,0,0,0,0,0,0,0};
    float16v ar = zv, az = zv, anx = zv, anh = zv;
    #pragma unroll
    for (int p = 0; p < 32; ++p){
        asm volatile("s_waitcnt vmcnt(0)" ::: "memory");  // phase-p B staged
        __builtin_amdgcn_s_barrier();
        __builtin_amdgcn_sched_barrier(0);
        // issue stage for phase p+1 (its buffer was consumed in phase p-1,
        // and those ds_reads completed before their waves hit the barrier)
        if (p + 1 < 32){
            unsigned short* db = Bs + ((p + 1) & 1) * 12288;
            gload_lds16(g0 + (p + 1) * 512, db + s0 * 512);
            gload_lds16(g1 + (p + 1) * 512, db + s1 * 512);
            gload_lds16(g2 + (p + 1) * 512, db + s2 * 512);
        }
        // compute phase p
        const unsigned short* bp = Bs + (p & 1) * 12288;
        const unsigned short* ap_ = (p < 16) ? As : (As + 8192);
        int kl = p & 15;
        short8 a  = *reinterpret_cast<const short8*>(
                        ap_ + arow * 256 + (((kl * 2 + half) ^ rl) << 3));
        short8 vr = *reinterpret_cast<const short8*>(bp + (0 * 8 + ct) * 512 + lane * 8);
        short8 vz = *reinterpret_cast<const short8*>(bp + (1 * 8 + ct) * 512 + lane * 8);
        short8 vn = *reinterpret_cast<const short8*>(bp + (2 * 8 + ct) * 512 + lane * 8);
        __builtin_amdgcn_s_setprio(1);
        ar = __builtin_amdgcn_mfma_f32_32x32x16_bf16(a, vr, ar, 0, 0, 0);
        az = __builtin_amdgcn_mfma_f32_32x32x16_bf16(a, vz, az, 0, 0, 0);
        if (p < 16) anx = __builtin_amdgcn_mfma_f32_32x32x16_bf16(a, vn, anx, 0, 0, 0);
        else        anh = __builtin_amdgcn_mfma_f32_32x32x16_bf16(a, vn, anh, 0, 0, 0);
        __builtin_amdgcn_s_setprio(0);
    }
    // fused GRU epilogue; H0 rows are L2-hot (read in prologue by this block)
    int cg = ct * 32 + l31;
    float rb = bih[cg] + bhh[cg];
    float zb = bih[256 + cg] + bhh[256 + cg];
    float bin = bih[512 + cg], bhn = bhh[512 + cg];
    #pragma unroll
    for (int r = 0; r < 16; ++r){
        int m = m0 + (r & 3) + 8 * (r >> 2) + 4 * half;
        if (m < N_DSTN){
            float h0v = H0[(size_t)m * 256 + cg];
            float rrg = 1.f / (1.f + __expf(-(ar[r] + rb)));
            float zg  = 1.f / (1.f + __expf(-(az[r] + zb)));
            float nx = anx[r] + bin + rrg * (anh[r] + bhn);
            float tm = __expf(-2.f * fabsf(nx));
            float nn = (1.f - tm) / (1.f + tm);
            nn = (nx >= 0.f) ? nn : -nn;
            outH[(size_t)m * 256 + cg] = (1.f - zg) * nn + zg * h0v;
        }
    }
}

// ---- logits = h @ W_out + b_out ------------------------------------------
__global__ __launch_bounds__(256) void logits_kernel(
        const float* __restrict__ H, const float* __restrict__ Wout,
        const float* __restrict__ bout, float* __restrict__ outL){
    __shared__ float Hl[16 * 260];
    __shared__ float Wl[16 * 260];
    int tid = threadIdx.x;
    int m0 = blockIdx.x * 16;
    #pragma unroll
    for (int i = 0; i < 4; ++i){
        int ci = tid + i * 256;
        int row = ci >> 6;
        int c4 = (ci & 63) << 2;
        int gr = m0 + row; if (gr >= N_DSTN) gr = N_DSTN - 1;
        float4 v = *reinterpret_cast<const float4*>(H + (size_t)gr * 256 + c4);
        float* dp = Hl + row * 260 + c4;
        dp[0] = v.x; dp[1] = v.y; dp[2] = v.z; dp[3] = v.w;
    }
    #pragma unroll
    for (int i = 0; i < 16; ++i){
        int ci = tid + i * 256;
        int c = ci >> 4, j = ci & 15;
        Wl[j * 260 + c] = Wout[c * 16 + j];
    }
    __syncthreads();
    int row = tid >> 4, j = tid & 15;
    const float* hr = Hl + row * 260;
    const float* wr = Wl + j * 260;
    float acc = bout[j];
    #pragma unroll
    for (int c = 0; c < 256; c += 4){
        float4 hv = *reinterpret_cast<const float4*>(hr + c);
        float4 wv = *reinterpret_cast<const float4*>(wr + c);
        acc = fmaf(hv.x, wv.x, fmaf(hv.y, wv.y, fmaf(hv.z, wv.z, fmaf(hv.w, wv.w, acc))));
    }
    int m = m0 + row;
    if (m < N_DSTN) outL[m * 16 + j] = acc;
}

extern "C" void kernel_launch(void* const* d_in, const int* in_sizes, int n_in,
                              void* d_out, int out_size, void* d_ws, size_t ws_size,
                              hipStream_t stream){
    const float* feat_gt = (const float*)d_in[0];
    const float* feat_ag = (const float*)d_in[1];
    const float* h0      = (const float*)d_in[2];
    const int*   e_src   = (const int*)d_in[3];
    const int*   e_dst   = (const int*)d_in[4];
    const float* W_src   = (const float*)d_in[5];
    const float* b_src   = (const float*)d_in[6];
    const float* W_dst   = (const float*)d_in[7];
    const float* b_dst   = (const float*)d_in[8];
    const float* attn    = (const float*)d_in[9];
    const float* W_res   = (const float*)d_in[10];
    const float* b_res   = (const float*)d_in[11];
    const float* W_ih    = (const float*)d_in[12];
    const float* W_hh    = (const float*)d_in[13];
    const float* b_ih    = (const float*)d_in[14];
    const float* b_hh    = (const float*)d_in[15];
    const float* W_out   = (const float*)d_in[16];
    const float* b_out   = (const float*)d_in[17];

    float* outL = (float*)d_out;
    float* outH = outL + (size_t)N_DSTN * 16;

    char* ws = (char*)d_ws;
    size_t off = 0;
    auto alloc = [&](size_t bytes) -> void* {
        void* p = ws + off; off = (off + bytes + 255) & ~(size_t)255; return p;
    };
    unsigned short* fs   = (unsigned short*)alloc((size_t)N_SRCN * 256 * 2);
    unsigned short* fd   = (unsigned short*)alloc((size_t)N_DSTN * 256 * 2);
    unsigned short* res  = (unsigned short*)alloc((size_t)N_DSTN * 256 * 2);
    unsigned short* xb   = (unsigned short*)alloc((size_t)N_DSTN * 256 * 2);
    unsigned short* Wt2  = (unsigned short*)alloc(49152 * 2);
    unsigned short* Wf   = (unsigned short*)alloc(393216 * 2);
    int* deg    = (int*)alloc(N_DSTN * 4);
    int* ptr    = (int*)alloc(N_DSTN * 4);
    int* cursor = (int*)alloc(N_DSTN * 4);
    int* csr    = (int*)alloc((size_t)NE * 4);
    int* bsum   = (int*)alloc(256 * 4);
    int* boff   = (int*)alloc(256 * 4);

    hipMemsetAsync(deg, 0, N_DSTN * 4, stream);
    pack_kernel<<<1728, 256, 0, stream>>>(W_src, W_dst, W_res, W_ih, W_hh, Wt2, Wf);

    proj_kernel<<<dim3(4, 782, 3), 256, 0, stream>>>(feat_gt, feat_ag, Wt2,
                                                     b_src, b_dst, b_res, fs, fd, res);

    degree_kernel<<<3125, 256, 0, stream>>>(e_dst, deg);
    scan1_kernel<<<196, 256, 0, stream>>>(deg, bsum);
    scan2_kernel<<<1, 256, 0, stream>>>(bsum, boff);
    scan3_kernel<<<196, 256, 0, stream>>>(deg, boff, ptr, cursor);
    scatter_kernel<<<3125, 256, 0, stream>>>(e_src, e_dst, cursor, csr);
    aggregate_kernel<<<12500, 256, 0, stream>>>(fs, fd, res, attn, ptr, deg, csr, xb);

    gru_kernel<<<1563, 512, 0, stream>>>(xb, h0, Wf, b_ih, b_hh, outH);
    logits_kernel<<<3125, 256, 0, stream>>>(outH, W_out, b_out, outL);
}

// Round 7
// 446.711 us; speedup vs baseline: 4.2771x; 1.0226x over previous
//
#include <hip/hip_runtime.h>
#include <stdint.h>

#define N_SRCN 50000
#define N_DSTN 50000
#define NE     800000
#define HIDN   256
#define NEG    0.2f

typedef __attribute__((ext_vector_type(8)))  short short8;
typedef __attribute__((ext_vector_type(16))) float float16v;

__device__ __forceinline__ float bf2f(unsigned short u){
    union { unsigned u32; float f; } c; c.u32 = ((unsigned)u) << 16; return c.f;
}
__device__ __forceinline__ unsigned short f2bf(float f){
    union { float f; unsigned u; } c; c.f = f;
    unsigned r = c.u + 0x7fffu + ((c.u >> 16) & 1u);
    return (unsigned short)(r >> 16);
}
__device__ __forceinline__ float4 ld4b(const unsigned short* p){
    uint2 u = *reinterpret_cast<const uint2*>(p);
    float4 r;
    r.x = bf2f((unsigned short)(u.x & 0xffff));
    r.y = bf2f((unsigned short)(u.x >> 16));
    r.z = bf2f((unsigned short)(u.y & 0xffff));
    r.w = bf2f((unsigned short)(u.y >> 16));
    return r;
}
// async 16B global -> LDS (wave-uniform LDS base + lane*16 dest; PER-LANE src)
__device__ __forceinline__ void gload_lds16(const unsigned short* g, unsigned short* l){
    __builtin_amdgcn_global_load_lds(
        (const __attribute__((address_space(1))) void*)g,
        (__attribute__((address_space(3))) void*)l,
        16, 0, 0);
}

// ---- pack weights, input-indexed (coalesced reads, scattered 2B writes) ----
// Wt2: [which(3)][cb(8)][kk(4)][lane(64)][8]   (49152)
// Wf : [cb(8)][kk(32)][gate(3)][lane(64)][8]   (393216), K=512 = [Wih|Whh]
//      gates adjacent per (cb,kk): one base addr + imm offsets 0/1024/2048 B
__global__ void pack_kernel(const float* __restrict__ Wsrc, const float* __restrict__ Wdst,
                            const float* __restrict__ Wres, const float* __restrict__ Wih,
                            const float* __restrict__ Whh,
                            unsigned short* __restrict__ Wt2,
                            unsigned short* __restrict__ Wf){
    int i = blockIdx.x * 256 + threadIdx.x;
    if (i < 49152){
        int which = i >> 14, j = i & 16383;          // j = k*256 + c
        int k = j >> 8, c = j & 255;
        const float* W = (which == 0) ? Wsrc : (which == 1 ? Wdst : Wres);
        float v = W[j];
        int off = which * 16384 + (c >> 5) * 2048 + (k >> 4) * 512
                + (((k >> 3) & 1) * 32 + (c & 31)) * 8 + (k & 7);
        Wt2[off] = f2bf(v);
    } else if (i < 49152 + 196608){
        int o = i - 49152;                            // Wih flat: (g*256+c)*256+k
        int row = o >> 8, k = o & 255;
        int g = row >> 8, c = row & 255;
        float v = Wih[o];
        int off = (c >> 5) * 49152 + (k >> 4) * 1536 + g * 512
                + (((k >> 3) & 1) * 32 + (c & 31)) * 8 + (k & 7);
        Wf[off] = f2bf(v);
    } else if (i < 49152 + 393216){
        int o = i - 49152 - 196608;                   // Whh
        int row = o >> 8, k = o & 255;
        int g = row >> 8, c = row & 255;
        float v = Whh[o];
        int off = (c >> 5) * 49152 + (16 + (k >> 4)) * 1536 + g * 512
                + (((k >> 3) & 1) * 32 + (c & 31)) * 8 + (k & 7);
        Wf[off] = f2bf(v);
    }
}

// ---- fused projection GEMM (K=64), z selects {src, dst, res} --------------
__global__ __launch_bounds__(256) void proj_kernel(
        const float* __restrict__ Agt, const float* __restrict__ Aag,
        const unsigned short* __restrict__ Wt2,
        const float* __restrict__ bsrc, const float* __restrict__ bdst,
        const float* __restrict__ bres,
        unsigned short* __restrict__ fs, unsigned short* __restrict__ fd,
        unsigned short* __restrict__ resb){
    __shared__ unsigned short As[64 * 72];
    __shared__ unsigned short Cs[64 * 72];
    int z = blockIdx.z;
    const float* A = (z == 0) ? Agt : Aag;
    const float* bias = (z == 0) ? bsrc : (z == 1 ? bdst : bres);
    unsigned short* out = (z == 0) ? fs : (z == 1 ? fd : resb);
    const unsigned short* Wb = Wt2 + z * 16384;
    int tid = threadIdx.x;
    int m0 = blockIdx.y * 64;
    #pragma unroll
    for (int i = 0; i < 4; ++i){
        int ci = tid + i * 256;
        int row = ci >> 4;
        int k4 = (ci & 15) << 2;
        int gr = m0 + row; if (gr >= N_SRCN) gr = N_SRCN - 1;
        float4 v = *reinterpret_cast<const float4*>(A + (size_t)gr * 64 + k4);
        unsigned short* dp = As + row * 72 + k4;
        dp[0] = f2bf(v.x); dp[1] = f2bf(v.y); dp[2] = f2bf(v.z); dp[3] = f2bf(v.w);
    }
    __syncthreads();
    int lane = tid & 63, w = tid >> 6;
    int l31 = lane & 31, half = lane >> 5;
    int msub = (w & 1) * 32;
    int cbw = blockIdx.x * 2 + (w >> 1);
    const unsigned short* bb = Wb + cbw * 2048 + lane * 8;
    const unsigned short* ap = As + (msub + l31) * 72 + half * 8;
    float16v acc = {0,0,0,0,0,0,0,0,0,0,0,0,0,0,0,0};
    #pragma unroll
    for (int ks = 0; ks < 4; ++ks){
        short8 a = *reinterpret_cast<const short8*>(ap + ks * 16);
        short8 b = *reinterpret_cast<const short8*>(bb + ks * 512);
        acc = __builtin_amdgcn_mfma_f32_32x32x16_bf16(a, b, acc, 0, 0, 0);
    }
    float bv = bias[cbw * 32 + l31];
    int ccol = (w >> 1) * 32 + l31;
    #pragma unroll
    for (int r = 0; r < 16; ++r){
        int row = (r & 3) + 8 * (r >> 2) + 4 * half + msub;
        Cs[row * 72 + ccol] = f2bf(acc[r] + bv);
    }
    __syncthreads();
    int srow = tid >> 2, chunk = tid & 3;
    int gr2 = m0 + srow;
    if (gr2 < N_SRCN){
        const uint4* sp = reinterpret_cast<const uint4*>(Cs + srow * 72 + chunk * 16);
        uint4* gp = reinterpret_cast<uint4*>(out + (size_t)gr2 * 256 + blockIdx.x * 64 + chunk * 16);
        gp[0] = sp[0];
        gp[1] = sp[1];
    }
}

// ---- edge CSR build -------------------------------------------------------
__global__ void degree_kernel(const int* __restrict__ dst, int* __restrict__ deg){
    int i = blockIdx.x * 256 + threadIdx.x;
    if (i < NE) atomicAdd(&deg[dst[i]], 1);
}

__global__ void scan1_kernel(const int* __restrict__ deg, int* __restrict__ bsum){
    __shared__ int s[256];
    int tid = threadIdx.x;
    int i = blockIdx.x * 256 + tid;
    s[tid] = (i < N_DSTN) ? deg[i] : 0;
    __syncthreads();
    #pragma unroll
    for (int off = 128; off; off >>= 1){
        if (tid < off) s[tid] += s[tid + off];
        __syncthreads();
    }
    if (tid == 0) bsum[blockIdx.x] = s[0];
}

__global__ void scan2_kernel(const int* __restrict__ bsum, int* __restrict__ boff){
    __shared__ int s[256];
    int tid = threadIdx.x;
    int v = (tid < 196) ? bsum[tid] : 0;
    s[tid] = v;
    __syncthreads();
    #pragma unroll
    for (int off = 1; off < 256; off <<= 1){
        int t = (tid >= off) ? s[tid - off] : 0;
        __syncthreads();
        s[tid] += t;
        __syncthreads();
    }
    if (tid < 196) boff[tid] = s[tid] - v;
}

__global__ void scan3_kernel(const int* __restrict__ deg, const int* __restrict__ boff,
                             int* __restrict__ ptr, int* __restrict__ cursor){
    __shared__ int s[256];
    int tid = threadIdx.x;
    int i = blockIdx.x * 256 + tid;
    int v = (i < N_DSTN) ? deg[i] : 0;
    s[tid] = v;
    __syncthreads();
    #pragma unroll
    for (int off = 1; off < 256; off <<= 1){
        int t = (tid >= off) ? s[tid - off] : 0;
        __syncthreads();
        s[tid] += t;
        __syncthreads();
    }
    int ex = s[tid] - v + boff[blockIdx.x];
    if (i < N_DSTN){ ptr[i] = ex; cursor[i] = ex; }
}

__global__ void scatter_kernel(const int* __restrict__ src, const int* __restrict__ dst,
                               int* __restrict__ cursor, int* __restrict__ csr){
    int i = blockIdx.x * 256 + threadIdx.x;
    if (i < NE){
        int d = dst[i];
        int pos = atomicAdd(&cursor[d], 1);
        csr[pos] = src[i];
    }
}

// ---- per-dst aggregation, no online max (exp safe here), 4-deep pipeline --
__global__ __launch_bounds__(256) void aggregate_kernel(
        const unsigned short* __restrict__ fs, const unsigned short* __restrict__ fd,
        const unsigned short* __restrict__ res, const float* __restrict__ attn,
        const int* __restrict__ ptr, const int* __restrict__ deg,
        const int* __restrict__ csr, unsigned short* __restrict__ x){
    int wv = threadIdx.x >> 6;
    int d = blockIdx.x * 4 + wv;
    if (d >= N_DSTN) return;
    int lane = threadIdx.x & 63;
    int c4 = lane * 4;
    float4 fdv = ld4b(fd + (size_t)d * 256 + c4);
    float4 at = *reinterpret_cast<const float4*>(attn + (lane >> 4) * 64 + (lane & 15) * 4);
    int p = ptr[d], dg = deg[d];
    float l = 0.f;
    float4 acc = make_float4(0.f, 0.f, 0.f, 0.f);
    for (int base = 0; base < dg; base += 64){
        int cnt = min(64, dg - base);
        int sreg = (lane < cnt) ? csr[p + base + lane] : 0;
        float4 b0 = ld4b(fs + (size_t)__shfl(sreg, 0) * 256 + c4);
        float4 b1 = ld4b(fs + (size_t)__shfl(sreg, 1 & 63) * 256 + c4);
        float4 b2 = ld4b(fs + (size_t)__shfl(sreg, 2 & 63) * 256 + c4);
        float4 b3 = ld4b(fs + (size_t)__shfl(sreg, 3 & 63) * 256 + c4);
        for (int j = 0; j < cnt; j += 4){
            float4 n0 = ld4b(fs + (size_t)__shfl(sreg, (j + 4) & 63) * 256 + c4);
            float4 n1 = ld4b(fs + (size_t)__shfl(sreg, (j + 5) & 63) * 256 + c4);
            float4 n2 = ld4b(fs + (size_t)__shfl(sreg, (j + 6) & 63) * 256 + c4);
            float4 n3 = ld4b(fs + (size_t)__shfl(sreg, (j + 7) & 63) * 256 + c4);
#define PROC(BV, T) { \
            float ex = BV.x + fdv.x; ex = ex > 0.f ? ex : NEG * ex; \
            float ey = BV.y + fdv.y; ey = ey > 0.f ? ey : NEG * ey; \
            float ez = BV.z + fdv.z; ez = ez > 0.f ? ez : NEG * ez; \
            float ew = BV.w + fdv.w; ew = ew > 0.f ? ew : NEG * ew; \
            float part = ex * at.x + ey * at.y + ez * at.z + ew * at.w; \
            part += __shfl_xor(part, 1); \
            part += __shfl_xor(part, 2); \
            part += __shfl_xor(part, 4); \
            part += __shfl_xor(part, 8); \
            float wgt = ((j + (T)) < cnt) ? __expf(part) : 0.f; \
            l += wgt; \
            acc.x = fmaf(wgt, BV.x, acc.x); \
            acc.y = fmaf(wgt, BV.y, acc.y); \
            acc.z = fmaf(wgt, BV.z, acc.z); \
            acc.w = fmaf(wgt, BV.w, acc.w); }
            PROC(b0, 0) PROC(b1, 1) PROC(b2, 2) PROC(b3, 3)
#undef PROC
            b0 = n0; b1 = n1; b2 = n2; b3 = n3;
        }
    }
    float inv = (l > 0.f) ? 1.f / l : 0.f;
    float4 rv = ld4b(res + (size_t)d * 256 + c4);
    float xx = fmaxf(fmaf(acc.x, inv, rv.x), 0.f);
    float xy = fmaxf(fmaf(acc.y, inv, rv.y), 0.f);
    float xz = fmaxf(fmaf(acc.z, inv, rv.z), 0.f);
    float xw = fmaxf(fmaf(acc.w, inv, rv.w), 0.f);
    uint2 o;
    o.x = (unsigned)f2bf(xx) | ((unsigned)f2bf(xy) << 16);
    o.y = (unsigned)f2bf(xz) | ((unsigned)f2bf(xw) << 16);
    *reinterpret_cast<uint2*>(x + (size_t)d * 256 + c4) = o;
}

// ---- GRU v11: barrier-free K-loop; B direct global->reg; A-only in LDS ----
// v7-v10 post-mortem: dur pinned at 122-124us across counted-vmcnt, 2blk/CU,
// conflict-free LDS -> the invariant was the per-phase barrier+vmcnt convoy.
// Realization: B staging into LDS had ZERO cross-wave reuse (wave ct reads
// only its own 3KB of each 24KB slice) -- the barriers existed only to
// protect buffers that never needed sharing. v11: only A (the truly shared
// operand) lives in LDS (32KB, staged once, ONE barrier). B streams directly
// global->VGPR per wave from the repacked gate-adjacent Wf (one base addr,
// imm offsets 0/1024/2048). No K-loop barriers: 16 free-running waves/CU
// (2 blocks x 8 @ <=128 unified regs) hide L2 latency via TLP + unrolled ILP.
__global__ __launch_bounds__(512, 4) void gru_kernel(
        const unsigned short* __restrict__ Xb,
        const float* __restrict__ H0, const unsigned short* __restrict__ Wf,
        const float* __restrict__ bih, const float* __restrict__ bhh,
        float* __restrict__ outH){
    __shared__ unsigned short As[2 * 32 * 256];  // 32KB: [X 32x256][H 32x256]
    int tid = threadIdx.x;
    int m0 = blockIdx.x << 5;                    // 32 rows/block
    int w = tid >> 6, lane = tid & 63;

    // ---- prologue A: X region via async gload (swizzled SOURCE, linear dest)
    #pragma unroll
    for (int i = 0; i < 2; ++i){
        int g = w + i * 8;                       // 0..15, rows {2g, 2g+1}
        int row = 2 * g + (lane >> 5);
        int gr = m0 + row; if (gr >= N_DSTN) gr = N_DSTN - 1;
        int j = lane & 31;
        const unsigned short* src = Xb + (size_t)gr * 256 + ((j ^ (row & 15)) << 3);
        gload_lds16(src, As + g * 512);
    }
    // ---- prologue A: H region reg-staged f32->bf16 (once per element)
    {
        int hrow = tid >> 4, hseg = tid & 15;    // 32 rows x 16 segs of 16 f32
        int hgr = m0 + hrow; if (hgr >= N_DSTN) hgr = N_DSTN - 1;
        const float* hp = H0 + (size_t)hgr * 256 + hseg * 16;
        float4 f0 = *reinterpret_cast<const float4*>(hp);
        float4 f1 = *reinterpret_cast<const float4*>(hp + 4);
        float4 f2 = *reinterpret_cast<const float4*>(hp + 8);
        float4 f3 = *reinterpret_cast<const float4*>(hp + 12);
        int rl = hrow & 15;
        int c0 = hseg * 2;
        uint4 o;
        o.x = (unsigned)f2bf(f0.x) | ((unsigned)f2bf(f0.y) << 16);
        o.y = (unsigned)f2bf(f0.z) | ((unsigned)f2bf(f0.w) << 16);
        o.z = (unsigned)f2bf(f1.x) | ((unsigned)f2bf(f1.y) << 16);
        o.w = (unsigned)f2bf(f1.z) | ((unsigned)f2bf(f1.w) << 16);
        *reinterpret_cast<uint4*>(As + 8192 + hrow * 256 + ((c0 ^ rl) << 3)) = o;
        o.x = (unsigned)f2bf(f2.x) | ((unsigned)f2bf(f2.y) << 16);
        o.y = (unsigned)f2bf(f2.z) | ((unsigned)f2bf(f2.w) << 16);
        o.z = (unsigned)f2bf(f3.x) | ((unsigned)f2bf(f3.y) << 16);
        o.w = (unsigned)f2bf(f3.z) | ((unsigned)f2bf(f3.w) << 16);
        *reinterpret_cast<uint4*>(As + 8192 + hrow * 256 + (((c0 + 1) ^ rl) << 3)) = o;
    }
    asm volatile("s_waitcnt vmcnt(0) lgkmcnt(0)" ::: "memory");
    __syncthreads();                             // the ONLY barrier

    int l31 = lane & 31, half = lane >> 5;
    int ct = w;                                  // 8 col-tiles of 32
    int rl = l31 & 15;
    const unsigned short* bb = Wf + ct * 49152 + lane * 8;   // gate-adjacent
    float16v zv = {0,0,0,0,0,0,0,0,0,0,0,0,0,0,0,0};
    float16v ar = zv, az = zv, anx = zv, anh = zv;
    #pragma unroll
    for (int p = 0; p < 32; ++p){
        const unsigned short* bp = bb + p * 1536;
        short8 vr = *reinterpret_cast<const short8*>(bp);          // off 0
        short8 vz = *reinterpret_cast<const short8*>(bp + 512);    // off 1024B
        short8 vn = *reinterpret_cast<const short8*>(bp + 1024);   // off 2048B
        const unsigned short* ap_ = (p < 16) ? As : (As + 8192);
        int kl = p & 15;
        short8 a = *reinterpret_cast<const short8*>(
                       ap_ + l31 * 256 + (((kl * 2 + half) ^ rl) << 3));
        ar = __builtin_amdgcn_mfma_f32_32x32x16_bf16(a, vr, ar, 0, 0, 0);
        az = __builtin_amdgcn_mfma_f32_32x32x16_bf16(a, vz, az, 0, 0, 0);
        if (p < 16) anx = __builtin_amdgcn_mfma_f32_32x32x16_bf16(a, vn, anx, 0, 0, 0);
        else        anh = __builtin_amdgcn_mfma_f32_32x32x16_bf16(a, vn, anh, 0, 0, 0);
    }
    // fused GRU epilogue; H0 rows are L2-hot (read in prologue by this block)
    int cg = ct * 32 + l31;
    float rb = bih[cg] + bhh[cg];
    float zb = bih[256 + cg] + bhh[256 + cg];
    float bin = bih[512 + cg], bhn = bhh[512 + cg];
    #pragma unroll
    for (int r = 0; r < 16; ++r){
        int m = m0 + (r & 3) + 8 * (r >> 2) + 4 * half;
        if (m < N_DSTN){
            float h0v = H0[(size_t)m * 256 + cg];
            float rrg = 1.f / (1.f + __expf(-(ar[r] + rb)));
            float zg  = 1.f / (1.f + __expf(-(az[r] + zb)));
            float nx = anx[r] + bin + rrg * (anh[r] + bhn);
            float tm = __expf(-2.f * fabsf(nx));
            float nn = (1.f - tm) / (1.f + tm);
            nn = (nx >= 0.f) ? nn : -nn;
            outH[(size_t)m * 256 + cg] = (1.f - zg) * nn + zg * h0v;
        }
    }
}

// ---- logits = h @ W_out + b_out ------------------------------------------
__global__ __launch_bounds__(256) void logits_kernel(
        const float* __restrict__ H, const float* __restrict__ Wout,
        const float* __restrict__ bout, float* __restrict__ outL){
    __shared__ float Hl[16 * 260];
    __shared__ float Wl[16 * 260];
    int tid = threadIdx.x;
    int m0 = blockIdx.x * 16;
    #pragma unroll
    for (int i = 0; i < 4; ++i){
        int ci = tid + i * 256;
        int row = ci >> 6;
        int c4 = (ci & 63) << 2;
        int gr = m0 + row; if (gr >= N_DSTN) gr = N_DSTN - 1;
        float4 v = *reinterpret_cast<const float4*>(H + (size_t)gr * 256 + c4);
        float* dp = Hl + row * 260 + c4;
        dp[0] = v.x; dp[1] = v.y; dp[2] = v.z; dp[3] = v.w;
    }
    #pragma unroll
    for (int i = 0; i < 16; ++i){
        int ci = tid + i * 256;
        int c = ci >> 4, j = ci & 15;
        Wl[j * 260 + c] = Wout[c * 16 + j];
    }
    __syncthreads();
    int row = tid >> 4, j = tid & 15;
    const float* hr = Hl + row * 260;
    const float* wr = Wl + j * 260;
    float acc = bout[j];
    #pragma unroll
    for (int c = 0; c < 256; c += 4){
        float4 hv = *reinterpret_cast<const float4*>(hr + c);
        float4 wv = *reinterpret_cast<const float4*>(wr + c);
        acc = fmaf(hv.x, wv.x, fmaf(hv.y, wv.y, fmaf(hv.z, wv.z, fmaf(hv.w, wv.w, acc))));
    }
    int m = m0 + row;
    if (m < N_DSTN) outL[m * 16 + j] = acc;
}

extern "C" void kernel_launch(void* const* d_in, const int* in_sizes, int n_in,
                              void* d_out, int out_size, void* d_ws, size_t ws_size,
                              hipStream_t stream){
    const float* feat_gt = (const float*)d_in[0];
    const float* feat_ag = (const float*)d_in[1];
    const float* h0      = (const float*)d_in[2];
    const int*   e_src   = (const int*)d_in[3];
    const int*   e_dst   = (const int*)d_in[4];
    const float* W_src   = (const float*)d_in[5];
    const float* b_src   = (const float*)d_in[6];
    const float* W_dst   = (const float*)d_in[7];
    const float* b_dst   = (const float*)d_in[8];
    const float* attn    = (const float*)d_in[9];
    const float* W_res   = (const float*)d_in[10];
    const float* b_res   = (const float*)d_in[11];
    const float* W_ih    = (const float*)d_in[12];
    const float* W_hh    = (const float*)d_in[13];
    const float* b_ih    = (const float*)d_in[14];
    const float* b_hh    = (const float*)d_in[15];
    const float* W_out   = (const float*)d_in[16];
    const float* b_out   = (const float*)d_in[17];

    float* outL = (float*)d_out;
    float* outH = outL + (size_t)N_DSTN * 16;

    char* ws = (char*)d_ws;
    size_t off = 0;
    auto alloc = [&](size_t bytes) -> void* {
        void* p = ws + off; off = (off + bytes + 255) & ~(size_t)255; return p;
    };
    unsigned short* fs   = (unsigned short*)alloc((size_t)N_SRCN * 256 * 2);
    unsigned short* fd   = (unsigned short*)alloc((size_t)N_DSTN * 256 * 2);
    unsigned short* res  = (unsigned short*)alloc((size_t)N_DSTN * 256 * 2);
    unsigned short* xb   = (unsigned short*)alloc((size_t)N_DSTN * 256 * 2);
    unsigned short* Wt2  = (unsigned short*)alloc(49152 * 2);
    unsigned short* Wf   = (unsigned short*)alloc(393216 * 2);
    int* deg    = (int*)alloc(N_DSTN * 4);
    int* ptr    = (int*)alloc(N_DSTN * 4);
    int* cursor = (int*)alloc(N_DSTN * 4);
    int* csr    = (int*)alloc((size_t)NE * 4);
    int* bsum   = (int*)alloc(256 * 4);
    int* boff   = (int*)alloc(256 * 4);

    hipMemsetAsync(deg, 0, N_DSTN * 4, stream);
    pack_kernel<<<1728, 256, 0, stream>>>(W_src, W_dst, W_res, W_ih, W_hh, Wt2, Wf);

    proj_kernel<<<dim3(4, 782, 3), 256, 0, stream>>>(feat_gt, feat_ag, Wt2,
                                                     b_src, b_dst, b_res, fs, fd, res);

    degree_kernel<<<3125, 256, 0, stream>>>(e_dst, deg);
    scan1_kernel<<<196, 256, 0, stream>>>(deg, bsum);
    scan2_kernel<<<1, 256, 0, stream>>>(bsum, boff);
    scan3_kernel<<<196, 256, 0, stream>>>(deg, boff, ptr, cursor);
    scatter_kernel<<<3125, 256, 0, stream>>>(e_src, e_dst, cursor, csr);
    aggregate_kernel<<<12500, 256, 0, stream>>>(fs, fd, res, attn, ptr, deg, csr, xb);

    gru_kernel<<<1563, 512, 0, stream>>>(xb, h0, Wf, b_ih, b_hh, outH);
    logits_kernel<<<3125, 256, 0, stream>>>(outH, W_out, b_out, outL);
}